// Round 5
// baseline (1225.523 us; speedup 1.0000x reference)
//
#include <hip/hip_runtime.h>

// ============================ shared arg struct ============================
struct Args {
  const float* x;
  const float* W[6];
  const float* b[6];
  const float* g[5];
  const float* be[5];
  float* out;
  unsigned* Bt1;            // [128 words][512 cols] layer-1 weight bits (transposed)
  unsigned* ByT;            // 5 x [16 words][512 cols]
  int* bs;                  // [6][512] bias signs (+1/-1)
  int* gs;                  // [5][512] col sums (int, exact)
  unsigned long long* gq;   // [5][512] col sumsq (u64, exact)
  unsigned* bar;            // barrier words: [0]=arrival count, [32]=generation
};

// ---- custom grid barrier: read-only polling, leader-only fences ----
// Arrival: one agent-scope fetch_add per block. Wait: read-only agent-scope
// polling of a generation word on a separate cache line + s_sleep backoff.
// Co-residency: 1024 blocks = 4 blocks/CU x 256 CUs — geometry PROVEN to
// co-schedule in round 2 (measured occupancy 48.6%, no hang). LDS 39936B
// (x4 = 156KB <= 160KB) and __launch_bounds__(256,4) (VGPR cap 128) bind
// exactly at 4 blocks/CU. Host memsets bar to 0 before each launch.
__device__ __forceinline__ void gridbar(unsigned* bar, unsigned target)
{
  __syncthreads();                         // all block work done
  if (threadIdx.x == 0) {
    __threadfence();                       // release: write back dirty L2
    unsigned prev = __hip_atomic_fetch_add(&bar[0], 1u, __ATOMIC_RELAXED,
                                           __HIP_MEMORY_SCOPE_AGENT);
    if (prev == gridDim.x - 1) {           // last arriver
      __hip_atomic_store(&bar[0], 0u, __ATOMIC_RELAXED,
                         __HIP_MEMORY_SCOPE_AGENT);
      __hip_atomic_store(&bar[32], target, __ATOMIC_RELEASE,
                         __HIP_MEMORY_SCOPE_AGENT);
    } else {
      while (__hip_atomic_load(&bar[32], __ATOMIC_RELAXED,
                               __HIP_MEMORY_SCOPE_AGENT) < target)
        __builtin_amdgcn_s_sleep(2);       // ~0.1us poll period, read-only
    }
    __threadfence();                       // acquire: invalidate stale L2
  }
  __syncthreads();
}

// ===================== THE kernel: one persistent grid =====================
// 1024 blocks x 256 thr (4/CU, 16 waves/CU = 4 waves/SIMD), 16 rows/block
// resident for the whole net. COLUMN-SPLIT: wave wv owns row group
// rg8 = wv>>1 (8 rows) and column half = wv&1 (256 cols), y[8][4] in regs.
// r=8 LDS amortization kept (round 2: r=4 is LDS-pipe-bound); 4 waves/SIMD
// for latency hiding (round 3 was latency-bound: VALU 34%, HBM 8.5%,
// occupancy 24% = 2 waves/SIMD). Both half-waves of a row group load the
// same x lines (L1/L2 reuse; unique HBM traffic unchanged). Layers 2..6
// exchange per-row A-bit words through 1KB LDS. Exact-int BN stats;
// 6 read-only-spin grid barriers.
__global__ __launch_bounds__(256, 4) void bnn_all(Args a)
{
  __shared__ __align__(16) unsigned Bsw[16 * 512];   // 32 KB: L1 dbuf / whole ByT layer
  __shared__ __align__(16) float thrbuf[1536];       // 6 KB; aliased by red_s/red_q
  __shared__ __align__(16) unsigned AwX[16 * 16];    // 1 KB: A-bit exchange (layers 2..6)
  int* red_s = (int*)thrbuf;
  int* red_q = red_s + 512;

  const int tid = threadIdx.x;
  const int lane = tid & 63;
  const int wv = tid >> 6;          // 0..3
  const int half = wv & 1;          // column half (0: cols 0-255, 1: 256-511)
  const int rg8 = wv >> 1;          // row group 0..1 (8 rows each)
  const int colbase = half << 8;
  const int row0 = blockIdx.x * 16;
  int ep = 0;                       // barrier epoch (uniform control flow)

  // ---------- phase 0: zero stats + pack weight/bias sign bits ----------
  {
    int idx = blockIdx.x * 256 + tid;
    if (idx < 7680) ((int*)a.gs)[idx] = 0;   // gs(10240B)+gq(20480B) contiguous
  }
  for (int R = blockIdx.x; R < 1885; R += 1024) {
    int l, n;
    if      (R < 500)  { l = 0; n = R; }
    else if (R < 900)  { l = 1; n = R - 500; }
    else if (R < 1250) { l = 2; n = R - 900; }
    else if (R < 1550) { l = 3; n = R - 1250; }
    else if (R < 1850) { l = 4; n = R - 1550; }
    else               { l = 5; n = R - 1850; }
    const int Ks[6] = {4096, 500, 400, 350, 300, 300};
    int K = Ks[l];
    int chunks = (l == 0) ? 64 : 8;
    unsigned* Bout = (l == 0) ? a.Bt1 : (a.ByT + (size_t)(l - 1) * 16 * 512);
    const float* Wrow = a.W[l] + (size_t)n * K;
    for (int c = wv; c < chunks; c += 4) {
      int k = c * 64 + lane;
      bool pred = (k < K) && (Wrow[k] >= 0.0f);
      unsigned long long m = __ballot(pred);
      if (lane == 0) {
        Bout[(size_t)(2 * c) * 512 + n]     = (unsigned)m;
        Bout[(size_t)(2 * c + 1) * 512 + n] = (unsigned)(m >> 32);
      }
    }
    if (tid == 0) a.bs[l * 512 + n] = (a.b[l][n] >= 0.0f) ? 1 : -1;
  }

  // prefetch x chunk kc=0 into regs BEFORE the barrier (hides under barrier wait)
  const float* xbase = a.x + (size_t)(row0 + rg8 * 8) * 4096 + lane;
  float xv[8][4];
#pragma unroll
  for (int r = 0; r < 8; r++)
#pragma unroll
    for (int cb = 0; cb < 4; cb++)
      xv[r][cb] = xbase[(size_t)r * 4096 + cb * 64];

  gridbar(a.bar, ++ep);

  // ---------- layer 1: x read once -> y[8][4] registers ----------
  // prologue: stage B chunk 0 (8 words x 512 cols = 16KB) into buf0
  {
    const uint4* src = (const uint4*)a.Bt1;
#pragma unroll
    for (int i = 0; i < 4; i++)
      ((uint4*)Bsw)[i * 256 + tid] = src[i * 256 + tid];
  }

  int y[8][4];
#pragma unroll
  for (int r = 0; r < 8; r++)
#pragma unroll
    for (int j = 0; j < 4; j++) y[r][j] = 0;

  for (int kc = 0; kc < 16; kc++) {        // 16 chunks of 256 K-bits (8 words)
    // ballots from prefetched xv -> Aw in SGPRs (wave-uniform)
    unsigned Aw[8][8];
#pragma unroll
    for (int r = 0; r < 8; r++)
#pragma unroll
      for (int cb = 0; cb < 4; cb++) {
        unsigned long long m = __ballot(xv[r][cb] >= 0.0f);
        Aw[r][2 * cb]     = (unsigned)m;
        Aw[r][2 * cb + 1] = (unsigned)(m >> 32);
      }
    // prefetch x chunk kc+1 (WAR on xv: issued after ballots consume regs)
    if (kc < 15) {
#pragma unroll
      for (int r = 0; r < 8; r++)
#pragma unroll
        for (int cb = 0; cb < 4; cb++)
          xv[r][cb] = xbase[(size_t)r * 4096 + (kc + 1) * 256 + cb * 64];
    }
    __syncthreads();   // buf[kc&1] fully staged (prev iter's post-popc writes)
    // stage-loads for kc+1 issue now; ds_writes deferred to after popc (T14)
    uint4 sbuf[4];
    if (kc < 15) {
      const uint4* src = (const uint4*)(a.Bt1 + (size_t)(kc + 1) * 4096);
#pragma unroll
      for (int i = 0; i < 4; i++) sbuf[i] = src[i * 256 + tid];
    }
    const unsigned* B = Bsw + (kc & 1) * 4096;
#pragma unroll
    for (int w = 0; w < 8; w++) {
#pragma unroll
      for (int jj = 0; jj < 4; jj++) {
        unsigned bw = B[(w << 9) + colbase + (jj << 6) + lane];
#pragma unroll
        for (int r = 0; r < 8; r++)
          y[r][jj] += __popc(Aw[r][w] ^ bw);
      }
    }
    if (kc < 15) {
      uint4* dst = (uint4*)Bsw + (size_t)((kc + 1) & 1) * 1024;
#pragma unroll
      for (int i = 0; i < 4; i++) dst[i * 256 + tid] = sbuf[i];
    }
  }
#pragma unroll
  for (int jj = 0; jj < 4; jj++) {
    int col = colbase + (jj << 6) + lane;
    int bsv = (col < 500) ? a.bs[col] : 0;
#pragma unroll
    for (int r = 0; r < 8; r++) y[r][jj] = 4096 - 2 * y[r][jj] + bsv;
  }
  // layer-1 stats (slot 0)
  {
    __syncthreads();
    red_s[tid] = 0; red_s[tid + 256] = 0;
    red_q[tid] = 0; red_q[tid + 256] = 0;
    __syncthreads();
#pragma unroll
    for (int jj = 0; jj < 4; jj++) {
      int col = colbase + (jj << 6) + lane;
      if (col < 500) {
        int s = 0, q = 0;
#pragma unroll
        for (int r = 0; r < 8; r++) { s += y[r][jj]; q += y[r][jj] * y[r][jj]; }
        atomicAdd(&red_s[col], s);
        atomicAdd(&red_q[col], q);   // per-block <= 16*4097^2 < 2^31
      }
    }
    __syncthreads();
    for (int c = tid; c < 500; c += 256) {
      atomicAdd(&a.gs[c], red_s[c]);
      atomicAdd(&a.gq[c], (unsigned long long)(long long)red_q[c]);
    }
    gridbar(a.bar, ++ep);
  }

  // ---------- layers 2..6 ----------
  const int Kins[5]  = {500, 400, 350, 300, 300};
  const int Nouts[5] = {400, 350, 300, 300, 35};
#pragma unroll 1
  for (int li = 1; li <= 5; li++) {
    const int Kin  = Kins[li - 1];
    const int Nout = Nouts[li - 1];
    const bool final_layer = (li == 5);
    const int* gs_in = a.gs + (size_t)(li - 1) * 512;
    const unsigned long long* gq_in = a.gq + (size_t)(li - 1) * 512;
    const unsigned* Bl = a.ByT + (size_t)(li - 1) * 16 * 512;
    const int* bsl = a.bs + (size_t)li * 512;

    // stage whole 32KB B-slice: loads issue now, overlap the BN-threshold math
    // (prev gridbar's trailing __syncthreads guards Bsw/thrbuf reuse)
    uint4 bv[8];
#pragma unroll
    for (int i = 0; i < 8; i++) bv[i] = ((const uint4*)Bl)[i * 256 + tid];

    for (int k = tid; k < 512; k += 256) {
      float t = 0.f, sg = 0.f, cc = -1.f;
      if (k < Kin) {
        float m  = (float)gs_in[k] * (1.0f / 16384.0f);
        float ms = (float)gq_in[k] * (1.0f / 16384.0f);
        float var = fmaxf(ms - m * m, 0.0f);
        float gv = a.g[li - 1][k], be = a.be[li - 1][k];
        if (gv != 0.0f) {
          t = m - be * sqrtf(var + 1e-5f) / gv;
          sg = (gv > 0.0f) ? 1.0f : -1.0f;
          cc = 0.0f;
        } else { t = 0.0f; sg = 0.0f; cc = be; }
      }
      thrbuf[k] = t; thrbuf[512 + k] = sg; thrbuf[1024 + k] = cc;
    }
#pragma unroll
    for (int i = 0; i < 8; i++) ((uint4*)Bsw)[i * 256 + tid] = bv[i];
    __syncthreads();   // thrbuf + Bsw visible

    // ballots: each half-wave produces 8 of the 16 K-words per row -> AwX
#pragma unroll
    for (int cb = 0; cb < 4; cb++) {
      int k = colbase + (cb << 6) + lane;
      float t = thrbuf[k], sg = thrbuf[512 + k], cc = thrbuf[1024 + k];
#pragma unroll
      for (int r = 0; r < 8; r++) {
        bool p = (k < Kin) &&
                 ((((float)y[r][cb] - t) * sg + cc) >= 0.0f);
        unsigned long long m = __ballot(p);
        if (lane == 0)
          *(unsigned long long*)&AwX[(rg8 * 8 + r) * 16 + half * 8 + 2 * cb] = m;
      }
    }
    __syncthreads();   // AwX complete (sibling half-wave's words visible)

    int nacc[8][4];
#pragma unroll
    for (int r = 0; r < 8; r++)
#pragma unroll
      for (int j = 0; j < 4; j++) nacc[r][j] = 0;

#pragma unroll
    for (int w = 0; w < 16; w++) {
      unsigned awr[8];
#pragma unroll
      for (int r = 0; r < 8; r++) awr[r] = AwX[(rg8 * 8 + r) * 16 + w];  // broadcast
#pragma unroll
      for (int jj = 0; jj < 4; jj++) {
        unsigned bw = Bsw[(w << 9) + colbase + (jj << 6) + lane];
#pragma unroll
        for (int r = 0; r < 8; r++)
          nacc[r][jj] += __popc(awr[r] ^ bw);
      }
    }
#pragma unroll
    for (int jj = 0; jj < 4; jj++) {
      int col = colbase + (jj << 6) + lane;
      int bsv = (col < Nout) ? bsl[col] : 0;
#pragma unroll
      for (int r = 0; r < 8; r++) {
        int v = Kin - 2 * nacc[r][jj] + bsv;
        y[r][jj] = v;
        if (final_layer && col < 35)
          a.out[(size_t)(row0 + rg8 * 8 + r) * 35 + col] = (float)v;
      }
    }
    if (!final_layer) {
      int* gs_out = a.gs + (size_t)li * 512;
      unsigned long long* gq_out = a.gq + (size_t)li * 512;
      __syncthreads();   // all thrbuf/AwX reads done before red_s rewrite
      red_s[tid] = 0; red_s[tid + 256] = 0;
      red_q[tid] = 0; red_q[tid + 256] = 0;
      __syncthreads();
#pragma unroll
      for (int jj = 0; jj < 4; jj++) {
        int col = colbase + (jj << 6) + lane;
        if (col < Nout) {
          int s = 0, q = 0;
#pragma unroll
          for (int r = 0; r < 8; r++) { s += y[r][jj]; q += y[r][jj] * y[r][jj]; }
          atomicAdd(&red_s[col], s);
          atomicAdd(&red_q[col], q);
        }
      }
      __syncthreads();
      for (int c = tid; c < Nout; c += 256) {
        atomicAdd(&gs_out[c], red_s[c]);
        atomicAdd(&gq_out[c], (unsigned long long)(long long)red_q[c]);
      }
      gridbar(a.bar, ++ep);
    }
  }
}

// ================================ host ================================
// Single unambiguous path. Co-residency of 1024 blocks (4/CU x 256 CUs):
// geometry proven in round 2 (48.6% occupancy, ran correctly). LDS 39936B
// -> 4/CU; __launch_bounds__(256,4) -> VGPR cap 128 -> 4 waves/EU.
extern "C" void kernel_launch(void* const* d_in, const int* in_sizes, int n_in,
                              void* d_out, int out_size, void* d_ws, size_t ws_size,
                              hipStream_t stream)
{
  (void)in_sizes; (void)n_in; (void)out_size; (void)ws_size;
  char* ws = (char*)d_ws;
  unsigned* Bt1 = (unsigned*)(ws);
  unsigned* ByT = (unsigned*)(ws + 262144);
  int* bs       = (int*)(ws + 425984);
  int* gs       = (int*)(ws + 438272);
  unsigned long long* gq = (unsigned long long*)(ws + 448512);
  unsigned* bar = (unsigned*)(ws + 469504);   // 2 cache lines: count / gen

  Args ka;
  ka.x    = (const float*)d_in[0];
  ka.W[0] = (const float*)d_in[1];  ka.b[0] = (const float*)d_in[2];
  ka.W[1] = (const float*)d_in[5];  ka.b[1] = (const float*)d_in[6];
  ka.W[2] = (const float*)d_in[9];  ka.b[2] = (const float*)d_in[10];
  ka.W[3] = (const float*)d_in[13]; ka.b[3] = (const float*)d_in[14];
  ka.W[4] = (const float*)d_in[17]; ka.b[4] = (const float*)d_in[18];
  ka.W[5] = (const float*)d_in[21]; ka.b[5] = (const float*)d_in[22];
  ka.g[0] = (const float*)d_in[3];  ka.be[0] = (const float*)d_in[4];
  ka.g[1] = (const float*)d_in[7];  ka.be[1] = (const float*)d_in[8];
  ka.g[2] = (const float*)d_in[11]; ka.be[2] = (const float*)d_in[12];
  ka.g[3] = (const float*)d_in[15]; ka.be[3] = (const float*)d_in[16];
  ka.g[4] = (const float*)d_in[19]; ka.be[4] = (const float*)d_in[20];
  ka.out = (float*)d_out;
  ka.Bt1 = Bt1; ka.ByT = ByT; ka.bs = bs; ka.gs = gs; ka.gq = gq;
  ka.bar = bar;

  hipMemsetAsync(ws + 469504, 0, 256, stream);   // barrier count + gen = 0
  bnn_all<<<1024, 256, 0, stream>>>(ka);
}

// Round 6
// 1216.080 us; speedup vs baseline: 1.0078x; 1.0078x over previous
//
#include <hip/hip_runtime.h>

// ============================ shared arg struct ============================
struct Args {
  const float* x;
  const float* W[6];
  const float* b[6];
  const float* g[5];
  const float* be[5];
  float* out;
  unsigned* Bt1;            // [128 words][512 cols] layer-1 weight bits (transposed)
  unsigned* ByT;            // 5 x [16 words][512 cols]
  int* bs;                  // [6][512] bias signs (+1/-1)
  int* gs;                  // [5][512] col sums (int, exact)
  unsigned long long* gq;   // [5][512] col sumsq (u64, exact)
  unsigned* bar;            // barrier words: [0]=arrival count, [32]=generation
};

// ---- custom grid barrier: read-only polling, leader-only fences ----
// Arrival: one agent-scope fetch_add per block. Wait: read-only agent-scope
// polling of a generation word on a separate cache line + s_sleep backoff.
// Co-residency: 1024 blocks = 4 blocks/CU x 256 CUs. LDS 39936B (x4 = 156KB
// <= 160KB) and amdgpu_waves_per_eu(4,4) (VGPR budget exactly 128) bind at
// 4 blocks/CU. Host memsets bar to 0 before each launch.
__device__ __forceinline__ void gridbar(unsigned* bar, unsigned target)
{
  __syncthreads();                         // all block work done
  if (threadIdx.x == 0) {
    __threadfence();                       // release: write back dirty L2
    unsigned prev = __hip_atomic_fetch_add(&bar[0], 1u, __ATOMIC_RELAXED,
                                           __HIP_MEMORY_SCOPE_AGENT);
    if (prev == gridDim.x - 1) {           // last arriver
      __hip_atomic_store(&bar[0], 0u, __ATOMIC_RELAXED,
                         __HIP_MEMORY_SCOPE_AGENT);
      __hip_atomic_store(&bar[32], target, __ATOMIC_RELEASE,
                         __HIP_MEMORY_SCOPE_AGENT);
    } else {
      while (__hip_atomic_load(&bar[32], __ATOMIC_RELAXED,
                               __HIP_MEMORY_SCOPE_AGENT) < target)
        __builtin_amdgcn_s_sleep(2);       // ~0.1us poll period, read-only
    }
    __threadfence();                       // acquire: invalidate stale L2
  }
  __syncthreads();
}

// ===================== THE kernel: one persistent grid =====================
// 1024 blocks x 256 thr (4/CU, 16 waves/CU = 4 waves/SIMD), 16 rows/block.
// COLUMN-SPLIT: wave wv owns row group rg8 = wv>>1 (8 rows) and column half
// = wv&1 (256 cols), y[8][4] in regs. r=8 LDS amortization (round 2: r=4 is
// LDS-pipe-bound); 4 waves/SIMD for latency hiding (round 3: latency-bound).
//
// ROUND-5 LESSON: __launch_bounds__(256,4) let the allocator shrink to 64
// VGPRs (chasing 8 waves/EU) -> ~100 regs of live state spilled to scratch
// -> 1.0 GB FETCH + 1.1 GB WRITE of pure spill traffic, 933us. Fix: pin
// waves/EU to exactly 4 so the budget is exactly 512/4 = 128 VGPRs (live
// state ~100 fits, zero spill). Occupancy bin unchanged: 16 waves/CU.
__global__ __launch_bounds__(256)
__attribute__((amdgpu_waves_per_eu(4, 4)))
void bnn_all(Args a)
{
  __shared__ __align__(16) unsigned Bsw[16 * 512];   // 32 KB: L1 dbuf / whole ByT layer
  __shared__ __align__(16) float thrbuf[1536];       // 6 KB; aliased by red_s/red_q
  __shared__ __align__(16) unsigned AwX[16 * 16];    // 1 KB: A-bit exchange (layers 2..6)
  int* red_s = (int*)thrbuf;
  int* red_q = red_s + 512;

  const int tid = threadIdx.x;
  const int lane = tid & 63;
  const int wv = tid >> 6;          // 0..3
  const int half = wv & 1;          // column half (0: cols 0-255, 1: 256-511)
  const int rg8 = wv >> 1;          // row group 0..1 (8 rows each)
  const int colbase = half << 8;
  const int row0 = blockIdx.x * 16;
  int ep = 0;                       // barrier epoch (uniform control flow)

  // ---------- phase 0: zero stats + pack weight/bias sign bits ----------
  {
    int idx = blockIdx.x * 256 + tid;
    if (idx < 7680) ((int*)a.gs)[idx] = 0;   // gs(10240B)+gq(20480B) contiguous
  }
  for (int R = blockIdx.x; R < 1885; R += 1024) {
    int l, n;
    if      (R < 500)  { l = 0; n = R; }
    else if (R < 900)  { l = 1; n = R - 500; }
    else if (R < 1250) { l = 2; n = R - 900; }
    else if (R < 1550) { l = 3; n = R - 1250; }
    else if (R < 1850) { l = 4; n = R - 1550; }
    else               { l = 5; n = R - 1850; }
    const int Ks[6] = {4096, 500, 400, 350, 300, 300};
    int K = Ks[l];
    int chunks = (l == 0) ? 64 : 8;
    unsigned* Bout = (l == 0) ? a.Bt1 : (a.ByT + (size_t)(l - 1) * 16 * 512);
    const float* Wrow = a.W[l] + (size_t)n * K;
    for (int c = wv; c < chunks; c += 4) {
      int k = c * 64 + lane;
      bool pred = (k < K) && (Wrow[k] >= 0.0f);
      unsigned long long m = __ballot(pred);
      if (lane == 0) {
        Bout[(size_t)(2 * c) * 512 + n]     = (unsigned)m;
        Bout[(size_t)(2 * c + 1) * 512 + n] = (unsigned)(m >> 32);
      }
    }
    if (tid == 0) a.bs[l * 512 + n] = (a.b[l][n] >= 0.0f) ? 1 : -1;
  }

  // prefetch x chunk kc=0 into regs BEFORE the barrier (hides under barrier wait)
  const float* xbase = a.x + (size_t)(row0 + rg8 * 8) * 4096 + lane;
  float xv[8][4];
#pragma unroll
  for (int r = 0; r < 8; r++)
#pragma unroll
    for (int cb = 0; cb < 4; cb++)
      xv[r][cb] = xbase[(size_t)r * 4096 + cb * 64];

  gridbar(a.bar, ++ep);

  // ---------- layer 1: x read once -> y[8][4] registers ----------
  // prologue: stage B chunk 0 (8 words x 512 cols = 16KB) into buf0
  {
    const uint4* src = (const uint4*)a.Bt1;
#pragma unroll
    for (int i = 0; i < 4; i++)
      ((uint4*)Bsw)[i * 256 + tid] = src[i * 256 + tid];
  }

  int y[8][4];
#pragma unroll
  for (int r = 0; r < 8; r++)
#pragma unroll
    for (int j = 0; j < 4; j++) y[r][j] = 0;

  for (int kc = 0; kc < 16; kc++) {        // 16 chunks of 256 K-bits (8 words)
    // ballots from prefetched xv -> Aw in SGPRs (wave-uniform)
    unsigned Aw[8][8];
#pragma unroll
    for (int r = 0; r < 8; r++)
#pragma unroll
      for (int cb = 0; cb < 4; cb++) {
        unsigned long long m = __ballot(xv[r][cb] >= 0.0f);
        Aw[r][2 * cb]     = (unsigned)m;
        Aw[r][2 * cb + 1] = (unsigned)(m >> 32);
      }
    // prefetch x chunk kc+1 (WAR on xv: issued after ballots consume regs)
    if (kc < 15) {
#pragma unroll
      for (int r = 0; r < 8; r++)
#pragma unroll
        for (int cb = 0; cb < 4; cb++)
          xv[r][cb] = xbase[(size_t)r * 4096 + (kc + 1) * 256 + cb * 64];
    }
    __syncthreads();   // buf[kc&1] fully staged (prev iter's post-popc writes)
    // stage-loads for kc+1 issue now; ds_writes deferred to after popc (T14)
    uint4 sbuf[4];
    if (kc < 15) {
      const uint4* src = (const uint4*)(a.Bt1 + (size_t)(kc + 1) * 4096);
#pragma unroll
      for (int i = 0; i < 4; i++) sbuf[i] = src[i * 256 + tid];
    }
    const unsigned* B = Bsw + (kc & 1) * 4096;
#pragma unroll
    for (int w = 0; w < 8; w++) {
#pragma unroll
      for (int jj = 0; jj < 4; jj++) {
        unsigned bw = B[(w << 9) + colbase + (jj << 6) + lane];
#pragma unroll
        for (int r = 0; r < 8; r++)
          y[r][jj] += __popc(Aw[r][w] ^ bw);
      }
    }
    if (kc < 15) {
      uint4* dst = (uint4*)Bsw + (size_t)((kc + 1) & 1) * 1024;
#pragma unroll
      for (int i = 0; i < 4; i++) dst[i * 256 + tid] = sbuf[i];
    }
  }
#pragma unroll
  for (int jj = 0; jj < 4; jj++) {
    int col = colbase + (jj << 6) + lane;
    int bsv = (col < 500) ? a.bs[col] : 0;
#pragma unroll
    for (int r = 0; r < 8; r++) y[r][jj] = 4096 - 2 * y[r][jj] + bsv;
  }
  // layer-1 stats (slot 0)
  {
    __syncthreads();
    red_s[tid] = 0; red_s[tid + 256] = 0;
    red_q[tid] = 0; red_q[tid + 256] = 0;
    __syncthreads();
#pragma unroll
    for (int jj = 0; jj < 4; jj++) {
      int col = colbase + (jj << 6) + lane;
      if (col < 500) {
        int s = 0, q = 0;
#pragma unroll
        for (int r = 0; r < 8; r++) { s += y[r][jj]; q += y[r][jj] * y[r][jj]; }
        atomicAdd(&red_s[col], s);
        atomicAdd(&red_q[col], q);   // per-block <= 16*4097^2 < 2^31
      }
    }
    __syncthreads();
    for (int c = tid; c < 500; c += 256) {
      atomicAdd(&a.gs[c], red_s[c]);
      atomicAdd(&a.gq[c], (unsigned long long)(long long)red_q[c]);
    }
    gridbar(a.bar, ++ep);
  }

  // ---------- layers 2..6 ----------
  const int Kins[5]  = {500, 400, 350, 300, 300};
  const int Nouts[5] = {400, 350, 300, 300, 35};
#pragma unroll 1
  for (int li = 1; li <= 5; li++) {
    const int Kin  = Kins[li - 1];
    const int Nout = Nouts[li - 1];
    const bool final_layer = (li == 5);
    const int* gs_in = a.gs + (size_t)(li - 1) * 512;
    const unsigned long long* gq_in = a.gq + (size_t)(li - 1) * 512;
    const unsigned* Bl = a.ByT + (size_t)(li - 1) * 16 * 512;
    const int* bsl = a.bs + (size_t)li * 512;

    // stage whole 32KB B-slice: loads issue now, overlap the BN-threshold math
    // (prev gridbar's trailing __syncthreads guards Bsw/thrbuf reuse)
    uint4 bv[8];
#pragma unroll
    for (int i = 0; i < 8; i++) bv[i] = ((const uint4*)Bl)[i * 256 + tid];

    for (int k = tid; k < 512; k += 256) {
      float t = 0.f, sg = 0.f, cc = -1.f;
      if (k < Kin) {
        float m  = (float)gs_in[k] * (1.0f / 16384.0f);
        float ms = (float)gq_in[k] * (1.0f / 16384.0f);
        float var = fmaxf(ms - m * m, 0.0f);
        float gv = a.g[li - 1][k], be = a.be[li - 1][k];
        if (gv != 0.0f) {
          t = m - be * sqrtf(var + 1e-5f) / gv;
          sg = (gv > 0.0f) ? 1.0f : -1.0f;
          cc = 0.0f;
        } else { t = 0.0f; sg = 0.0f; cc = be; }
      }
      thrbuf[k] = t; thrbuf[512 + k] = sg; thrbuf[1024 + k] = cc;
    }
#pragma unroll
    for (int i = 0; i < 8; i++) ((uint4*)Bsw)[i * 256 + tid] = bv[i];
    __syncthreads();   // thrbuf + Bsw visible

    // ballots: each half-wave produces 8 of the 16 K-words per row -> AwX
#pragma unroll
    for (int cb = 0; cb < 4; cb++) {
      int k = colbase + (cb << 6) + lane;
      float t = thrbuf[k], sg = thrbuf[512 + k], cc = thrbuf[1024 + k];
#pragma unroll
      for (int r = 0; r < 8; r++) {
        bool p = (k < Kin) &&
                 ((((float)y[r][cb] - t) * sg + cc) >= 0.0f);
        unsigned long long m = __ballot(p);
        if (lane == 0)
          *(unsigned long long*)&AwX[(rg8 * 8 + r) * 16 + half * 8 + 2 * cb] = m;
      }
    }
    __syncthreads();   // AwX complete (sibling half-wave's words visible)

    int nacc[8][4];
#pragma unroll
    for (int r = 0; r < 8; r++)
#pragma unroll
      for (int j = 0; j < 4; j++) nacc[r][j] = 0;

#pragma unroll
    for (int w = 0; w < 16; w++) {
      unsigned awr[8];
#pragma unroll
      for (int r = 0; r < 8; r++) awr[r] = AwX[(rg8 * 8 + r) * 16 + w];  // broadcast
#pragma unroll
      for (int jj = 0; jj < 4; jj++) {
        unsigned bw = Bsw[(w << 9) + colbase + (jj << 6) + lane];
#pragma unroll
        for (int r = 0; r < 8; r++)
          nacc[r][jj] += __popc(awr[r] ^ bw);
      }
    }
#pragma unroll
    for (int jj = 0; jj < 4; jj++) {
      int col = colbase + (jj << 6) + lane;
      int bsv = (col < Nout) ? bsl[col] : 0;
#pragma unroll
      for (int r = 0; r < 8; r++) {
        int v = Kin - 2 * nacc[r][jj] + bsv;
        y[r][jj] = v;
        if (final_layer && col < 35)
          a.out[(size_t)(row0 + rg8 * 8 + r) * 35 + col] = (float)v;
      }
    }
    if (!final_layer) {
      int* gs_out = a.gs + (size_t)li * 512;
      unsigned long long* gq_out = a.gq + (size_t)li * 512;
      __syncthreads();   // all thrbuf/AwX reads done before red_s rewrite
      red_s[tid] = 0; red_s[tid + 256] = 0;
      red_q[tid] = 0; red_q[tid + 256] = 0;
      __syncthreads();
#pragma unroll
      for (int jj = 0; jj < 4; jj++) {
        int col = colbase + (jj << 6) + lane;
        if (col < Nout) {
          int s = 0, q = 0;
#pragma unroll
          for (int r = 0; r < 8; r++) { s += y[r][jj]; q += y[r][jj] * y[r][jj]; }
          atomicAdd(&red_s[col], s);
          atomicAdd(&red_q[col], q);
        }
      }
      __syncthreads();
      for (int c = tid; c < Nout; c += 256) {
        atomicAdd(&gs_out[c], red_s[c]);
        atomicAdd(&gq_out[c], (unsigned long long)(long long)red_q[c]);
      }
      gridbar(a.bar, ++ep);
    }
  }
}

// ================================ host ================================
// Single unambiguous path. Co-residency of 1024 blocks (4/CU x 256 CUs):
// LDS 39936B -> 4/CU; amdgpu_waves_per_eu(4,4) -> VGPR budget exactly 128
// -> 4 waves/EU -> 16 waves/CU. Geometry proven to co-schedule (rounds 2,5).
extern "C" void kernel_launch(void* const* d_in, const int* in_sizes, int n_in,
                              void* d_out, int out_size, void* d_ws, size_t ws_size,
                              hipStream_t stream)
{
  (void)in_sizes; (void)n_in; (void)out_size; (void)ws_size;
  char* ws = (char*)d_ws;
  unsigned* Bt1 = (unsigned*)(ws);
  unsigned* ByT = (unsigned*)(ws + 262144);
  int* bs       = (int*)(ws + 425984);
  int* gs       = (int*)(ws + 438272);
  unsigned long long* gq = (unsigned long long*)(ws + 448512);
  unsigned* bar = (unsigned*)(ws + 469504);   // 2 cache lines: count / gen

  Args ka;
  ka.x    = (const float*)d_in[0];
  ka.W[0] = (const float*)d_in[1];  ka.b[0] = (const float*)d_in[2];
  ka.W[1] = (const float*)d_in[5];  ka.b[1] = (const float*)d_in[6];
  ka.W[2] = (const float*)d_in[9];  ka.b[2] = (const float*)d_in[10];
  ka.W[3] = (const float*)d_in[13]; ka.b[3] = (const float*)d_in[14];
  ka.W[4] = (const float*)d_in[17]; ka.b[4] = (const float*)d_in[18];
  ka.W[5] = (const float*)d_in[21]; ka.b[5] = (const float*)d_in[22];
  ka.g[0] = (const float*)d_in[3];  ka.be[0] = (const float*)d_in[4];
  ka.g[1] = (const float*)d_in[7];  ka.be[1] = (const float*)d_in[8];
  ka.g[2] = (const float*)d_in[11]; ka.be[2] = (const float*)d_in[12];
  ka.g[3] = (const float*)d_in[15]; ka.be[3] = (const float*)d_in[16];
  ka.g[4] = (const float*)d_in[19]; ka.be[4] = (const float*)d_in[20];
  ka.out = (float*)d_out;
  ka.Bt1 = Bt1; ka.ByT = ByT; ka.bs = bs; ka.gs = gs; ka.gq = gq;
  ka.bar = bar;

  hipMemsetAsync(ws + 469504, 0, 256, stream);   // barrier count + gen = 0
  bnn_all<<<1024, 256, 0, stream>>>(ka);
}